// Round 11
// baseline (892.900 us; speedup 1.0000x reference)
//
#include <hip/hip_runtime.h>

#define D_DIM 256
#define BM    32
#define NTHR  256
#define XPAD  264   // xn row stride (floats): 264 = 256+8 -> LN-write banks spread
#define WPAD  20    // wt row stride (floats): 16 k-values + 4 pad, keeps 16B align

// Pure fp32 VALU implementation. After R2-R10: every MFMA build showed a
// ~5e-2 error (10x beyond operand-quantization theory, f16 == bf16 error,
// call-to-call drift) -- signature of an occasional corrupted LDS fragment
// that 5 static audits could not find. This build removes the entire
// suspect surface: no MFMA, no XOR swizzle, no atomics, no d_ws, fp32 end
// to end. Error budget ~1e-5 vs 5.8e-2 threshold; deterministic.
// Roofline: 34.4 GFLOP fp32 / 157.3 TF = 219us ideal; register tile
// 2 rows x 16 cols per thread keeps LDS reads (18 b128 ~216cyc) under the
// fma stream (128 fma ~256cyc) per k-group -> compute-bound.
__global__ void fused_critic_f32(const float* __restrict__ feat,
                                 const float* __restrict__ gamma,
                                 const float* __restrict__ beta,
                                 const float* __restrict__ W1,
                                 const float* __restrict__ b1,
                                 const float* __restrict__ wv,
                                 const float* __restrict__ bv,
                                 float* __restrict__ out) {
    __shared__ float xn[BM * XPAD];     // 33.0 KB  LN output, fp32
    __shared__ float wt[D_DIM * WPAD];  // 20.5 KB  W1 k-slice, [col][k]

    const int tid   = threadIdx.x;
    const int brow0 = blockIdx.x * BM;

    // ---------------- LayerNorm: 8 threads per row ----------------
    {
        const int r = tid >> 3;          // 0..31
        const int t = tid & 7;
        const float4* f4 = (const float4*)(feat + (size_t)(brow0 + r) * D_DIM);
        float4 x[8];
        float s = 0.f, s2 = 0.f;
#pragma unroll
        for (int i = 0; i < 8; ++i) {
            float4 v = f4[i * 8 + t];
            x[i] = v;
            s  += v.x + v.y + v.z + v.w;
            s2 += v.x * v.x + v.y * v.y + v.z * v.z + v.w * v.w;
        }
        s += __shfl_xor(s, 1);  s2 += __shfl_xor(s2, 1);
        s += __shfl_xor(s, 2);  s2 += __shfl_xor(s2, 2);
        s += __shfl_xor(s, 4);  s2 += __shfl_xor(s2, 4);
        const float mean = s * (1.f / 256.f);
        const float var  = s2 * (1.f / 256.f) - mean * mean;
        const float rstd = rsqrtf(var + 1e-5f);

        const float4* g4  = (const float4*)gamma;
        const float4* be4 = (const float4*)beta;
#pragma unroll
        for (int i = 0; i < 8; ++i) {
            const int c = i * 8 + t;     // float4 column 0..63
            float4 g = g4[c], bb = be4[c], v = x[i], o;
            o.x = (v.x - mean) * rstd * g.x + bb.x;
            o.y = (v.y - mean) * rstd * g.y + bb.y;
            o.z = (v.z - mean) * rstd * g.z + bb.z;
            o.w = (v.w - mean) * rstd * g.w + bb.w;
            *(float4*)&xn[r * XPAD + c * 4] = o;
        }
    }

    // ---------------- GEMM: thread = rows {2ty,2ty+1} x cols {tx+16j} -----
    const int tx = tid & 15;
    const int ty = tid >> 4;             // 0..15

    float acc0[16], acc1[16];
#pragma unroll
    for (int jj = 0; jj < 16; ++jj) { acc0[jj] = 0.f; acc1[jj] = 0.f; }

    for (int kc = 0; kc < 16; ++kc) {    // 16 chunks of KT=16
        __syncthreads();                 // prev chunk consumed (or LN done)
        // stage W1[c][k0..k0+15] -> wt[c][0..15]; thread tid handles col c=tid
        {
            const float4* wsrc = (const float4*)(W1 + (size_t)tid * D_DIM + kc * 16);
            float* wdst = &wt[tid * WPAD];
#pragma unroll
            for (int q = 0; q < 4; ++q)
                *(float4*)&wdst[q * 4] = wsrc[q];
        }
        __syncthreads();                 // tile visible

#pragma unroll
        for (int g = 0; g < 4; ++g) {    // 4 k-values per group
            const int kb = kc * 16 + g * 4;
            float4 a0 = *(const float4*)&xn[(2 * ty)     * XPAD + kb];
            float4 a1 = *(const float4*)&xn[(2 * ty + 1) * XPAD + kb];
#pragma unroll
            for (int jj = 0; jj < 16; ++jj) {
                const int c = tx + 16 * jj;
                float4 w = *(const float4*)&wt[c * WPAD + g * 4];
                acc0[jj] = fmaf(a0.x, w.x, acc0[jj]);
                acc0[jj] = fmaf(a0.y, w.y, acc0[jj]);
                acc0[jj] = fmaf(a0.z, w.z, acc0[jj]);
                acc0[jj] = fmaf(a0.w, w.w, acc0[jj]);
                acc1[jj] = fmaf(a1.x, w.x, acc1[jj]);
                acc1[jj] = fmaf(a1.y, w.y, acc1[jj]);
                acc1[jj] = fmaf(a1.z, w.z, acc1[jj]);
                acc1[jj] = fmaf(a1.w, w.w, acc1[jj]);
            }
        }
    }

    // ---------------- epilogue: bias + SiLU + dot(Wv), deterministic ------
    float s0 = 0.f, s1 = 0.f;
#pragma unroll
    for (int jj = 0; jj < 16; ++jj) {
        const int c = tx + 16 * jj;
        const float bb  = b1[c];
        const float wvc = wv[c];
        const float h0 = acc0[jj] + bb;
        const float h1 = acc1[jj] + bb;
        s0 += (h0 / (1.f + __expf(-h0))) * wvc;   // SiLU = h*sigmoid(h)
        s1 += (h1 / (1.f + __expf(-h1))) * wvc;
    }
    // reduce over the 16 tx lanes (lane bits 0..3)
    s0 += __shfl_xor(s0, 1);  s1 += __shfl_xor(s1, 1);
    s0 += __shfl_xor(s0, 2);  s1 += __shfl_xor(s1, 2);
    s0 += __shfl_xor(s0, 4);  s1 += __shfl_xor(s1, 4);
    s0 += __shfl_xor(s0, 8);  s1 += __shfl_xor(s1, 8);
    if (tx == 0) {
        const float bvv = bv[0];
        out[brow0 + 2 * ty]     = s0 + bvv;
        out[brow0 + 2 * ty + 1] = s1 + bvv;
    }
}

extern "C" void kernel_launch(void* const* d_in, const int* in_sizes, int n_in,
                              void* d_out, int out_size, void* d_ws, size_t ws_size,
                              hipStream_t stream) {
    const float* feat  = (const float*)d_in[0];
    const float* gamma = (const float*)d_in[1];
    const float* beta  = (const float*)d_in[2];
    const float* W1    = (const float*)d_in[3];
    const float* b1    = (const float*)d_in[4];
    const float* wv    = (const float*)d_in[5];
    const float* bv    = (const float*)d_in[6];
    float* out = (float*)d_out;

    const int nblocks = out_size / BM;   // 262144/32 = 8192
    hipLaunchKernelGGL(fused_critic_f32, dim3(nblocks), dim3(NTHR), 0, stream,
                       feat, gamma, beta, W1, b1, wv, bv, out);
}

// Round 12
// 620.478 us; speedup vs baseline: 1.4391x; 1.4391x over previous
//
#include <hip/hip_runtime.h>

#define D_DIM 256
#define BM    32
#define NTHR  256
#define XPAD  264   // xn row stride (floats): 264 = 256+8 -> LN-write banks spread
#define WPAD  20    // wt row stride (floats): 16 k-values + 4 pad, keeps 16B align

// Pure fp32 VALU implementation (R11 PASSED: absmax 3.9e-3, 892us).
// R11 counters: VGPR=64 (no launch_bounds -> compiler occupancy heuristic),
// WRITE_SIZE 151MB vs 1MB output = register spill round-trips; VALUBusy 37%.
// Single-variable fix: __launch_bounds__(256,4) -> VGPR cap 128, live set
// ~75 fits, zero spill. LDS 54KB -> 2 blocks/CU = 16 waves/CU.
// Math/order byte-identical to R11 (absmax must stay 3.9e-3).
__global__ __launch_bounds__(NTHR, 4)
void fused_critic_f32(const float* __restrict__ feat,
                      const float* __restrict__ gamma,
                      const float* __restrict__ beta,
                      const float* __restrict__ W1,
                      const float* __restrict__ b1,
                      const float* __restrict__ wv,
                      const float* __restrict__ bv,
                      float* __restrict__ out) {
    __shared__ float xn[BM * XPAD];     // 33.0 KB  LN output, fp32
    __shared__ float wt[D_DIM * WPAD];  // 20.5 KB  W1 k-slice, [col][k]

    const int tid   = threadIdx.x;
    const int brow0 = blockIdx.x * BM;

    // ---------------- LayerNorm: 8 threads per row ----------------
    {
        const int r = tid >> 3;          // 0..31
        const int t = tid & 7;
        const float4* f4 = (const float4*)(feat + (size_t)(brow0 + r) * D_DIM);
        float4 x[8];
        float s = 0.f, s2 = 0.f;
#pragma unroll
        for (int i = 0; i < 8; ++i) {
            float4 v = f4[i * 8 + t];
            x[i] = v;
            s  += v.x + v.y + v.z + v.w;
            s2 += v.x * v.x + v.y * v.y + v.z * v.z + v.w * v.w;
        }
        s += __shfl_xor(s, 1);  s2 += __shfl_xor(s2, 1);
        s += __shfl_xor(s, 2);  s2 += __shfl_xor(s2, 2);
        s += __shfl_xor(s, 4);  s2 += __shfl_xor(s2, 4);
        const float mean = s * (1.f / 256.f);
        const float var  = s2 * (1.f / 256.f) - mean * mean;
        const float rstd = rsqrtf(var + 1e-5f);

        const float4* g4  = (const float4*)gamma;
        const float4* be4 = (const float4*)beta;
#pragma unroll
        for (int i = 0; i < 8; ++i) {
            const int c = i * 8 + t;     // float4 column 0..63
            float4 g = g4[c], bb = be4[c], v = x[i], o;
            o.x = (v.x - mean) * rstd * g.x + bb.x;
            o.y = (v.y - mean) * rstd * g.y + bb.y;
            o.z = (v.z - mean) * rstd * g.z + bb.z;
            o.w = (v.w - mean) * rstd * g.w + bb.w;
            *(float4*)&xn[r * XPAD + c * 4] = o;
        }
    }

    // ---------------- GEMM: thread = rows {2ty,2ty+1} x cols {tx+16j} -----
    const int tx = tid & 15;
    const int ty = tid >> 4;             // 0..15

    float acc0[16], acc1[16];
#pragma unroll
    for (int jj = 0; jj < 16; ++jj) { acc0[jj] = 0.f; acc1[jj] = 0.f; }

    for (int kc = 0; kc < 16; ++kc) {    // 16 chunks of KT=16
        __syncthreads();                 // prev chunk consumed (or LN done)
        // stage W1[c][k0..k0+15] -> wt[c][0..15]; thread tid handles col c=tid
        {
            const float4* wsrc = (const float4*)(W1 + (size_t)tid * D_DIM + kc * 16);
            float* wdst = &wt[tid * WPAD];
#pragma unroll
            for (int q = 0; q < 4; ++q)
                *(float4*)&wdst[q * 4] = wsrc[q];
        }
        __syncthreads();                 // tile visible

#pragma unroll
        for (int g = 0; g < 4; ++g) {    // 4 k-values per group
            const int kb = kc * 16 + g * 4;
            float4 a0 = *(const float4*)&xn[(2 * ty)     * XPAD + kb];
            float4 a1 = *(const float4*)&xn[(2 * ty + 1) * XPAD + kb];
#pragma unroll
            for (int jj = 0; jj < 16; ++jj) {
                const int c = tx + 16 * jj;
                float4 w = *(const float4*)&wt[c * WPAD + g * 4];
                acc0[jj] = fmaf(a0.x, w.x, acc0[jj]);
                acc0[jj] = fmaf(a0.y, w.y, acc0[jj]);
                acc0[jj] = fmaf(a0.z, w.z, acc0[jj]);
                acc0[jj] = fmaf(a0.w, w.w, acc0[jj]);
                acc1[jj] = fmaf(a1.x, w.x, acc1[jj]);
                acc1[jj] = fmaf(a1.y, w.y, acc1[jj]);
                acc1[jj] = fmaf(a1.z, w.z, acc1[jj]);
                acc1[jj] = fmaf(a1.w, w.w, acc1[jj]);
            }
        }
    }

    // ---------------- epilogue: bias + SiLU + dot(Wv), deterministic ------
    float s0 = 0.f, s1 = 0.f;
#pragma unroll
    for (int jj = 0; jj < 16; ++jj) {
        const int c = tx + 16 * jj;
        const float bb  = b1[c];
        const float wvc = wv[c];
        const float h0 = acc0[jj] + bb;
        const float h1 = acc1[jj] + bb;
        s0 += (h0 / (1.f + __expf(-h0))) * wvc;   // SiLU = h*sigmoid(h)
        s1 += (h1 / (1.f + __expf(-h1))) * wvc;
    }
    // reduce over the 16 tx lanes (lane bits 0..3)
    s0 += __shfl_xor(s0, 1);  s1 += __shfl_xor(s1, 1);
    s0 += __shfl_xor(s0, 2);  s1 += __shfl_xor(s1, 2);
    s0 += __shfl_xor(s0, 4);  s1 += __shfl_xor(s1, 4);
    s0 += __shfl_xor(s0, 8);  s1 += __shfl_xor(s1, 8);
    if (tx == 0) {
        const float bvv = bv[0];
        out[brow0 + 2 * ty]     = s0 + bvv;
        out[brow0 + 2 * ty + 1] = s1 + bvv;
    }
}

extern "C" void kernel_launch(void* const* d_in, const int* in_sizes, int n_in,
                              void* d_out, int out_size, void* d_ws, size_t ws_size,
                              hipStream_t stream) {
    const float* feat  = (const float*)d_in[0];
    const float* gamma = (const float*)d_in[1];
    const float* beta  = (const float*)d_in[2];
    const float* W1    = (const float*)d_in[3];
    const float* b1    = (const float*)d_in[4];
    const float* wv    = (const float*)d_in[5];
    const float* bv    = (const float*)d_in[6];
    float* out = (float*)d_out;

    const int nblocks = out_size / BM;   // 262144/32 = 8192
    hipLaunchKernelGGL(fused_critic_f32, dim3(nblocks), dim3(NTHR), 0, stream,
                       feat, gamma, beta, W1, b1, wv, bv, out);
}